// Round 3
// baseline (237.101 us; speedup 1.0000x reference)
//
#include <hip/hip_runtime.h>

#define NB 16
#define CC 4
#define HH 32
#define WW 32
#define SS 1024

// main: mapped[v][s][k*4+o] = sum_{u,c} unfold(x)[u,s,c,k] * mask[u,v] * cm[u,v,c,o] * W[u,v,s,c,o,k]
// block = (s-tile of 16, v); 576 threads = 16 sl x 36 float4-quads over the 144-float [c][o][k] row.
// Each thread accumulates over u only (one (c,o,k) per element); c-reduction done cross-thread in LDS.
__global__ __launch_bounds__(576) void main_kernel(
    const float* __restrict__ x,
    const float* __restrict__ wgt,
    const float* __restrict__ chan_map,
    const float* __restrict__ mask,
    float* __restrict__ mapped)
{
    __shared__ __align__(16) float XT[16 * 16 * 36];  // [u][sl][k*4+c]
    __shared__ __align__(16) float CM[16 * 16];       // [u][o*4+c]
    __shared__ __align__(16) float4 RED[16 * 36];     // [sl][q] c-partials
    const int v   = blockIdx.y;
    const int s0  = blockIdx.x * 16;
    const int tid = threadIdx.x;

    // fused unfold: stage X tile straight from x (x is 256KB fp32, L2-resident)
    for (int t = tid; t < 16 * 16 * 36; t += 576) {
        int u = t / 576;
        int rem = t % 576;
        int sl = rem / 36, kc = rem % 36;
        int k = kc >> 2, c = kc & 3;
        int s = s0 + sl;
        int h = (s >> 5) + (k / 3) - 1;
        int w = (s & 31) + (k % 3) - 1;
        float val = 0.f;
        if (h >= 0 && h < HH && w >= 0 && w < WW)
            val = x[((u * CC + c) * HH + h) * WW + w];
        XT[t] = val;
    }
    // combined chan_map*mask, transposed to [u][o][c]
    if (tid < 256) {
        int u = tid >> 4, o = (tid >> 2) & 3, c = tid & 3;
        CM[tid] = chan_map[((u * 16 + v) * 4 + c) * 4 + o] * mask[u * 16 + v];
    }
    __syncthreads();

    const int sl = tid / 36;
    const int q  = tid % 36;          // float4 index into the 144-float row
    const int s  = s0 + sl;

    // decompose the 4 row elements r=4q+e into (c,o,k); r = c*36 + o*9 + k
    int xt_off[4], cm_off[4];
#pragma unroll
    for (int e = 0; e < 4; ++e) {
        int r = 4 * q + e;
        int c = r / 36;
        int o = (r / 9) & 3;
        int k = r % 9;
        xt_off[e] = sl * 36 + k * 4 + c;
        cm_off[e] = o * 4 + c;
    }

    const float* wp = wgt + (size_t)v * 147456 + (size_t)s * 144 + 4 * q;
    float4 acc = make_float4(0.f, 0.f, 0.f, 0.f);
#pragma unroll 4
    for (int u = 0; u < 16; ++u) {
        float4 w4 = *(const float4*)(wp + (size_t)u * 2359296); // u stride = 16*147456 floats
        acc.x += w4.x * XT[u * 576 + xt_off[0]] * CM[u * 16 + cm_off[0]];
        acc.y += w4.y * XT[u * 576 + xt_off[1]] * CM[u * 16 + cm_off[1]];
        acc.z += w4.z * XT[u * 576 + xt_off[2]] * CM[u * 16 + cm_off[2]];
        acc.w += w4.w * XT[u * 576 + xt_off[3]] * CM[u * 16 + cm_off[3]];
    }

    // cross-thread c-reduction: threads {q, q+9, q+18, q+27} hold c=0..3 partials
    // for the same four (o,k) pairs (element-wise).
    RED[sl * 36 + q] = acc;
    __syncthreads();
    if (q < 9) {
        float4 t0 = RED[sl * 36 + q];
        float4 t1 = RED[sl * 36 + q + 9];
        float4 t2 = RED[sl * 36 + q + 18];
        float4 t3 = RED[sl * 36 + q + 27];
        float tot[4] = { t0.x + t1.x + t2.x + t3.x,
                         t0.y + t1.y + t2.y + t3.y,
                         t0.z + t1.z + t2.z + t3.z,
                         t0.w + t1.w + t2.w + t3.w };
        float* mp = mapped + v * (SS * 36) + s * 36;
#pragma unroll
        for (int e = 0; e < 4; ++e) {
            int r = 4 * q + e;        // r = o*9 + k  (c=0 block)
            int o = r / 9, k = r % 9;
            mp[k * 4 + o] = tot[e];
        }
    }
}

// fold with torch's channel reinterpretation: flat channel (k*4+o) is read back as (c*9+i*3+j)
__global__ void fold_kernel(const float* __restrict__ mapped, float* __restrict__ out) {
    int t = blockIdx.x * blockDim.x + threadIdx.x;
    if (t >= NB * CC * HH * WW) return;
    int xx = t & 31, y = (t >> 5) & 31, c = (t >> 10) & 3, v = t >> 12;
    float sum = 0.f;
#pragma unroll
    for (int i = 0; i < 3; ++i) {
        int h = y + 1 - i;
        if (h < 0 || h >= HH) continue;
#pragma unroll
        for (int j = 0; j < 3; ++j) {
            int w = xx + 1 - j;
            if (w < 0 || w >= WW) continue;
            sum += mapped[v * (SS * 36) + (h * 32 + w) * 36 + (c * 9 + i * 3 + j)];
        }
    }
    out[t] = sum;
}

extern "C" void kernel_launch(void* const* d_in, const int* in_sizes, int n_in,
                              void* d_out, int out_size, void* d_ws, size_t ws_size,
                              hipStream_t stream) {
    const float* x    = (const float*)d_in[0];
    const float* wgt  = (const float*)d_in[1];
    const float* cmap = (const float*)d_in[2];
    const float* mask = (const float*)d_in[3];
    float* out = (float*)d_out;

    float* mapped = (float*)d_ws;   // 16*1024*36 = 589,824 floats = 2.36 MB

    main_kernel<<<dim3(SS / 16, NB), 576, 0, stream>>>(x, wgt, cmap, mask, mapped);
    fold_kernel<<<(NB * CC * HH * WW + 255) / 256, 256, 0, stream>>>(mapped, out);
}

// Round 4
// 213.890 us; speedup vs baseline: 1.1085x; 1.1085x over previous
//
#include <hip/hip_runtime.h>

#define NB 16
#define CC 4
#define HH 32
#define WW 32
#define SS 1024

typedef float f4 __attribute__((ext_vector_type(4)));

// Kernel A: unfold x -> xu[u][s][k*4+c] fp32 (c innermost, matches main's LDS layout
// so main's staging is a straight contiguous float4 copy).
__global__ void unfold_kernel(const float* __restrict__ x, float* __restrict__ xu) {
    int idx = blockIdx.x * blockDim.x + threadIdx.x;
    if (idx >= NB * SS * 36) return;
    int c = idx & 3;
    int k = (idx >> 2) % 9;
    int s = (idx / 36) & (SS - 1);
    int u = idx / (SS * 36);
    int h = (s >> 5) + (k / 3) - 1;
    int w = (s & 31) + (k % 3) - 1;
    float v = 0.f;
    if (h >= 0 && h < HH && w >= 0 && w < WW)
        v = x[((u * CC + c) * HH + h) * WW + w];
    xu[idx] = v;
}

// Kernel B: mapped[v][s][k*4+o] = sum_{u,c} xu[u,s,k*4+c] * mask[u,v] * cm[u,v,c,o] * W[u,v,s,c,o,k]
// block = (s-tile of 16, v); 576 threads = 16 sl x 36 float4-quads over the 144-float [c][o][k] row.
// Each thread accumulates over u only (one (c,o,k) per vector element); c-reduction cross-thread in LDS.
__global__ __launch_bounds__(576) void main_kernel(
    const float* __restrict__ xu,
    const float* __restrict__ wgt,
    const float* __restrict__ chan_map,
    const float* __restrict__ mask,
    float* __restrict__ mapped)
{
    __shared__ __align__(16) float XT[16 * 16 * 36];  // [u][sl][k*4+c]
    __shared__ __align__(16) float CM[16 * 16];       // [u][o*4+c]
    __shared__ __align__(16) float4 RED[16 * 36];     // [sl][q] c-partials
    const int v   = blockIdx.y;
    const int s0  = blockIdx.x * 16;
    const int tid = threadIdx.x;

    // stage X tile: contiguous float4 copy, 2304 float4s, 4 per thread, fully coalesced
    {
        const f4* src = (const f4*)xu;
        f4* dst = (f4*)XT;
#pragma unroll
        for (int i = 0; i < 4; ++i) {
            int t = tid + i * 576;            // t in [0, 2304)
            int u = t / 144, r = t % 144;     // 144 float4 per u
            dst[t] = src[u * 9216 + s0 * 9 + r];
        }
    }
    // combined chan_map*mask, transposed to [u][o][c]
    if (tid < 256) {
        int u = tid >> 4, o = (tid >> 2) & 3, c = tid & 3;
        CM[tid] = chan_map[((u * 16 + v) * 4 + c) * 4 + o] * mask[u * 16 + v];
    }
    __syncthreads();

    const int sl = tid / 36;
    const int q  = tid % 36;          // float4 index into the 144-float row
    const int s  = s0 + sl;

    // decompose the 4 row elements r=4q+e into (c,o,k); r = c*36 + o*9 + k
    int xt_off[4], cm_off[4];
#pragma unroll
    for (int e = 0; e < 4; ++e) {
        int r = 4 * q + e;
        int c = r / 36;
        int o = (r / 9) & 3;
        int k = r % 9;
        xt_off[e] = sl * 36 + k * 4 + c;
        cm_off[e] = o * 4 + c;
    }

    const float* wp = wgt + (size_t)v * 147456 + (size_t)s * 144 + 4 * q;
    f4 acc = (f4)0.f;
#pragma unroll 4
    for (int u = 0; u < 16; ++u) {
        f4 w4 = __builtin_nontemporal_load((const f4*)(wp + (size_t)u * 2359296)); // u stride = 16*147456 floats
        acc.x += w4.x * XT[u * 576 + xt_off[0]] * CM[u * 16 + cm_off[0]];
        acc.y += w4.y * XT[u * 576 + xt_off[1]] * CM[u * 16 + cm_off[1]];
        acc.z += w4.z * XT[u * 576 + xt_off[2]] * CM[u * 16 + cm_off[2]];
        acc.w += w4.w * XT[u * 576 + xt_off[3]] * CM[u * 16 + cm_off[3]];
    }

    // cross-thread c-reduction: threads {q, q+9, q+18, q+27} hold c=0..3 partials
    // for the same four (o,k) pairs (element-wise).
    RED[sl * 36 + q] = make_float4(acc.x, acc.y, acc.z, acc.w);
    __syncthreads();
    if (q < 9) {
        float4 t0 = RED[sl * 36 + q];
        float4 t1 = RED[sl * 36 + q + 9];
        float4 t2 = RED[sl * 36 + q + 18];
        float4 t3 = RED[sl * 36 + q + 27];
        float tot[4] = { t0.x + t1.x + t2.x + t3.x,
                         t0.y + t1.y + t2.y + t3.y,
                         t0.z + t1.z + t2.z + t3.z,
                         t0.w + t1.w + t2.w + t3.w };
        float* mp = mapped + v * (SS * 36) + s * 36;
#pragma unroll
        for (int e = 0; e < 4; ++e) {
            int r = 4 * q + e;        // r = o*9 + k  (c=0 block)
            int o = r / 9, k = r % 9;
            mp[k * 4 + o] = tot[e];
        }
    }
}

// Kernel C: fold with torch's channel reinterpretation: flat channel (k*4+o) read back as (c*9+i*3+j)
__global__ void fold_kernel(const float* __restrict__ mapped, float* __restrict__ out) {
    int t = blockIdx.x * blockDim.x + threadIdx.x;
    if (t >= NB * CC * HH * WW) return;
    int xx = t & 31, y = (t >> 5) & 31, c = (t >> 10) & 3, v = t >> 12;
    float sum = 0.f;
#pragma unroll
    for (int i = 0; i < 3; ++i) {
        int h = y + 1 - i;
        if (h < 0 || h >= HH) continue;
#pragma unroll
        for (int j = 0; j < 3; ++j) {
            int w = xx + 1 - j;
            if (w < 0 || w >= WW) continue;
            sum += mapped[v * (SS * 36) + (h * 32 + w) * 36 + (c * 9 + i * 3 + j)];
        }
    }
    out[t] = sum;
}

extern "C" void kernel_launch(void* const* d_in, const int* in_sizes, int n_in,
                              void* d_out, int out_size, void* d_ws, size_t ws_size,
                              hipStream_t stream) {
    const float* x    = (const float*)d_in[0];
    const float* wgt  = (const float*)d_in[1];
    const float* cmap = (const float*)d_in[2];
    const float* mask = (const float*)d_in[3];
    float* out = (float*)d_out;

    float* xu     = (float*)d_ws;                 // 589,824 floats = 2.36 MB
    float* mapped = xu + NB * SS * 36;            // 589,824 floats = 2.36 MB

    unfold_kernel<<<(NB * SS * 36 + 255) / 256, 256, 0, stream>>>(x, xu);
    main_kernel<<<dim3(SS / 16, NB), 576, 0, stream>>>(xu, wgt, cmap, mask, mapped);
    fold_kernel<<<(NB * CC * HH * WW + 255) / 256, 256, 0, stream>>>(mapped, out);
}

// Round 5
// 213.320 us; speedup vs baseline: 1.1115x; 1.0027x over previous
//
#include <hip/hip_runtime.h>

#define NB 16
#define CC 4
#define HH 32
#define WW 32
#define SS 1024

typedef float f4 __attribute__((ext_vector_type(4)));

// Kernel A: unfold x -> xu[u][s][k*4+c] fp32 (c innermost, matches main's LDS layout
// so main's staging is a straight contiguous float4 copy).
__global__ void unfold_kernel(const float* __restrict__ x, float* __restrict__ xu) {
    int idx = blockIdx.x * blockDim.x + threadIdx.x;
    if (idx >= NB * SS * 36) return;
    int c = idx & 3;
    int k = (idx >> 2) % 9;
    int s = (idx / 36) & (SS - 1);
    int u = idx / (SS * 36);
    int h = (s >> 5) + (k / 3) - 1;
    int w = (s & 31) + (k % 3) - 1;
    float v = 0.f;
    if (h >= 0 && h < HH && w >= 0 && w < WW)
        v = x[((u * CC + c) * HH + h) * WW + w];
    xu[idx] = v;
}

// Kernel B: mapped[v][s][k*4+o] = sum_{u,c} xu[u,s,k*4+c] * mask[u,v] * cm[u,v,c,o] * W[u,v,s,c,o,k]
// block = (s-tile of 16, v-PAIR); 576 threads = 16 sl x 36 float4-quads over the 144-float [c][o][k] row.
// XT is v-independent: one staging serves both v slabs. grid = 512 = exactly 2 blocks/CU.
// Each thread accumulates over u only (one (c,o,k) per vector element, per v); c-reduction in LDS.
__global__ __launch_bounds__(576) void main_kernel(
    const float* __restrict__ xu,
    const float* __restrict__ wgt,
    const float* __restrict__ chan_map,
    const float* __restrict__ mask,
    float* __restrict__ mapped)
{
    __shared__ __align__(16) float XT[16 * 16 * 36];   // [u][sl][k*4+c]  36.9 KB
    __shared__ __align__(16) float CM[2 * 16 * 16];    // [vi][u][o*4+c]   2 KB
    __shared__ __align__(16) float4 RED[2 * 16 * 36];  // [vi][sl][q]     18.4 KB
    const int v0  = blockIdx.y * 2;
    const int s0  = blockIdx.x * 16;
    const int tid = threadIdx.x;

    // stage X tile: contiguous float4 copy, 2304 float4s, 4 per thread, fully coalesced
    {
        const f4* src = (const f4*)xu;
        f4* dst = (f4*)XT;
#pragma unroll
        for (int i = 0; i < 4; ++i) {
            int t = tid + i * 576;            // t in [0, 2304)
            int u = t / 144, r = t % 144;     // 144 float4 per u
            dst[t] = src[u * 9216 + s0 * 9 + r];
        }
    }
    // combined chan_map*mask for both v, transposed to [vi][u][o][c]
    if (tid < 512) {
        int vi = tid >> 8, rem = tid & 255;
        int u = rem >> 4, o = (rem >> 2) & 3, c = rem & 3;
        int v = v0 + vi;
        CM[tid] = chan_map[((u * 16 + v) * 4 + c) * 4 + o] * mask[u * 16 + v];
    }
    __syncthreads();

    const int sl = tid / 36;
    const int q  = tid % 36;          // float4 index into the 144-float row
    const int s  = s0 + sl;

    // decompose the 4 row elements r=4q+e into (c,o,k); r = c*36 + o*9 + k
    int xt_off[4], cm_off[4];
#pragma unroll
    for (int e = 0; e < 4; ++e) {
        int r = 4 * q + e;
        int c = r / 36;
        int o = (r / 9) & 3;
        int k = r % 9;
        xt_off[e] = sl * 36 + k * 4 + c;
        cm_off[e] = o * 4 + c;
    }

    const float* wp0 = wgt + (size_t)v0 * 147456 + (size_t)s * 144 + 4 * q;
    const float* wp1 = wp0 + 147456;
    f4 acc0 = (f4)0.f, acc1 = (f4)0.f;
#pragma unroll 4
    for (int u = 0; u < 16; ++u) {
        f4 wa = __builtin_nontemporal_load((const f4*)(wp0 + (size_t)u * 2359296));
        f4 wb = __builtin_nontemporal_load((const f4*)(wp1 + (size_t)u * 2359296));
        float x0 = XT[u * 576 + xt_off[0]], x1 = XT[u * 576 + xt_off[1]];
        float x2 = XT[u * 576 + xt_off[2]], x3 = XT[u * 576 + xt_off[3]];
        float ca0 = CM[u * 16 + cm_off[0]],       ca1 = CM[u * 16 + cm_off[1]];
        float ca2 = CM[u * 16 + cm_off[2]],       ca3 = CM[u * 16 + cm_off[3]];
        float cb0 = CM[256 + u * 16 + cm_off[0]], cb1 = CM[256 + u * 16 + cm_off[1]];
        float cb2 = CM[256 + u * 16 + cm_off[2]], cb3 = CM[256 + u * 16 + cm_off[3]];
        acc0.x += wa.x * x0 * ca0;  acc1.x += wb.x * x0 * cb0;
        acc0.y += wa.y * x1 * ca1;  acc1.y += wb.y * x1 * cb1;
        acc0.z += wa.z * x2 * ca2;  acc1.z += wb.z * x2 * cb2;
        acc0.w += wa.w * x3 * ca3;  acc1.w += wb.w * x3 * cb3;
    }

    // cross-thread c-reduction: threads {q, q+9, q+18, q+27} hold c=0..3 partials
    // for the same four (o,k) pairs (element-wise), per v.
    RED[sl * 36 + q]       = make_float4(acc0.x, acc0.y, acc0.z, acc0.w);
    RED[576 + sl * 36 + q] = make_float4(acc1.x, acc1.y, acc1.z, acc1.w);
    __syncthreads();
    if (q < 9) {
#pragma unroll
        for (int vi = 0; vi < 2; ++vi) {
            float4 t0 = RED[vi * 576 + sl * 36 + q];
            float4 t1 = RED[vi * 576 + sl * 36 + q + 9];
            float4 t2 = RED[vi * 576 + sl * 36 + q + 18];
            float4 t3 = RED[vi * 576 + sl * 36 + q + 27];
            float tot[4] = { t0.x + t1.x + t2.x + t3.x,
                             t0.y + t1.y + t2.y + t3.y,
                             t0.z + t1.z + t2.z + t3.z,
                             t0.w + t1.w + t2.w + t3.w };
            float* mp = mapped + (v0 + vi) * (SS * 36) + s * 36;
#pragma unroll
            for (int e = 0; e < 4; ++e) {
                int r = 4 * q + e;        // r = o*9 + k  (c=0 block)
                int o = r / 9, k = r % 9;
                mp[k * 4 + o] = tot[e];
            }
        }
    }
}

// Kernel C: fold with torch's channel reinterpretation: flat channel (k*4+o) read back as (c*9+i*3+j)
__global__ void fold_kernel(const float* __restrict__ mapped, float* __restrict__ out) {
    int t = blockIdx.x * blockDim.x + threadIdx.x;
    if (t >= NB * CC * HH * WW) return;
    int xx = t & 31, y = (t >> 5) & 31, c = (t >> 10) & 3, v = t >> 12;
    float sum = 0.f;
#pragma unroll
    for (int i = 0; i < 3; ++i) {
        int h = y + 1 - i;
        if (h < 0 || h >= HH) continue;
#pragma unroll
        for (int j = 0; j < 3; ++j) {
            int w = xx + 1 - j;
            if (w < 0 || w >= WW) continue;
            sum += mapped[v * (SS * 36) + (h * 32 + w) * 36 + (c * 9 + i * 3 + j)];
        }
    }
    out[t] = sum;
}

extern "C" void kernel_launch(void* const* d_in, const int* in_sizes, int n_in,
                              void* d_out, int out_size, void* d_ws, size_t ws_size,
                              hipStream_t stream) {
    const float* x    = (const float*)d_in[0];
    const float* wgt  = (const float*)d_in[1];
    const float* cmap = (const float*)d_in[2];
    const float* mask = (const float*)d_in[3];
    float* out = (float*)d_out;

    float* xu     = (float*)d_ws;                 // 589,824 floats = 2.36 MB
    float* mapped = xu + NB * SS * 36;            // 589,824 floats = 2.36 MB

    unfold_kernel<<<(NB * SS * 36 + 255) / 256, 256, 0, stream>>>(x, xu);
    main_kernel<<<dim3(SS / 16, NB / 2), 576, 0, stream>>>(xu, wgt, cmap, mask, mapped);
    fold_kernel<<<(NB * CC * HH * WW + 255) / 256, 256, 0, stream>>>(mapped, out);
}